// Round 14
// baseline (214.455 us; speedup 1.0000x reference)
//
#include <hip/hip_runtime.h>
#include <hip/hip_bf16.h>

// VectorQuantizer: z [8,64,64,64] fp32 (BCHW), embedding [8192,64] fp32.
// Outputs (concat): z_q [8,64,64,64] fp32 (BCHW), indices [32768] as fp32.
//
// R14: ||e_norm||^2 == 1 (const) -> dist = 2 - 2*dot: k_mfma drops se entirely
// (argmax dot, zero-seeded acc; recheck still uses exact se_half). NSTAGE 64->32
// (2x8KB dbuf = 16KB LDS) -> LDS block cap 5->10/CU to lift the 37% occupancy
// plateau; the two pixel-sets' 6-deep MFMA chains are interleaved (independent,
// dep-distance 2) so the matrix pipe stays busy through the VALU epilogue.
// Staging (R12, proven): global_load_lds 16B registerless from pre-swizzled
// codebook, LDS double-buffer, 1 barrier/stage, 0 bank conflicts.

#define NPIX 32768
#define NE   8192
#define EDIM 64
#define HW   4096
#define NSTAGE 32           // codes per LDS stage (2 subtiles of 16)
#define KSPLIT 8
#define CPS  (NE / KSPLIT)  // 1024 codes per split
#define NSTG (CPS / NSTAGE) // 32 stages per block
#define MARGIN 2.0e-4f      // in dot-space (= dist-gap/2, 2x safety vs 3e-5 err)

typedef short bf16x8 __attribute__((ext_vector_type(8)));
typedef float f32x4  __attribute__((ext_vector_type(4)));

__device__ __forceinline__ short f2bf_bits(float x) {
    __hip_bfloat16 h = __float2bfloat16(x);
    short s; __builtin_memcpy(&s, &h, 2); return s;
}
__device__ __forceinline__ float bf_hi_f(float x) {
    return __bfloat162float(__float2bfloat16(x));
}
// map float to unsigned with same total order
__device__ __forceinline__ unsigned int order_u32(float f) {
    unsigned int s = __float_as_uint(f);
    return (s & 0x80000000u) ? ~s : (s | 0x80000000u);
}
// async global->LDS, 16B/lane; HW writes lane i at lds_base + i*16 (wave-uniform base)
__device__ __forceinline__ void gload_lds16(const void* g, void* l) {
    __builtin_amdgcn_global_load_lds(
        (const __attribute__((address_space(1))) void*)g,
        (__attribute__((address_space(3))) void*)l, 16, 0, 0);
}

// ---------------- prep (fused): codebook (swizzled bf16 hi/lo) + pixels ------
// esw layout = the k_mfma LDS stage image: per 32-code stage, 8 combos
// (sub[2] x {hi-k0,hi-k1,lo-k0,lo-k1}) x 1KB; within combo, MFMA-B fragment
// order: slot frag_lane = (o&3)*16 + code_col holds 8 channels (16B).
__global__ __launch_bounds__(256) void k_prep(const float* __restrict__ emb,
                                              const float* __restrict__ z,
                                              float* __restrict__ e_norm,
                                              float* __restrict__ se_half,
                                              short* __restrict__ esw,
                                              float* __restrict__ zn,
                                              unsigned* __restrict__ counter) {
    if (blockIdx.x == 0 && threadIdx.x == 0) *counter = 0u;
    if (blockIdx.x < NE / 4) {
        // --- codebook: 1 code per wave, lane = channel ---
        const int wave = threadIdx.x >> 6;
        const int lane = threadIdx.x & 63;
        const int n = blockIdx.x * 4 + wave;
        float v = emb[n * EDIM + lane];
        float ss = v * v;
        #pragma unroll
        for (int off = 32; off; off >>= 1) ss += __shfl_xor(ss, off, 64);
        const float inv = 1.0f / fmaxf(sqrtf(ss), 1e-12f);
        const float en = v * inv;
        e_norm[n * EDIM + lane] = en;
        const float hf = bf_hi_f(en);
        // swizzled write (c = lane): 32-code stages
        const int stage = n >> 5, cs = n & 31;
        const int sub = cs >> 4, colb = cs & 15;
        const int o = lane >> 3, j = lane & 7;
        const int slot = ((o & 3) * 16 + colb) * 8 + j;
        short* sbase = esw + stage * 4096 + (sub * 4 + (o >> 2)) * 512;
        sbase[slot] = f2bf_bits(en);                 // hi combos (+0,+1)
        sbase[2 * 512 + slot] = f2bf_bits(en - hf);  // lo combos (+2,+3)
        float s2 = en * en;
        #pragma unroll
        for (int off = 32; off; off >>= 1) s2 += __shfl_xor(s2, off, 64);
        if (lane == 0) se_half[n] = 0.5f * s2;       // recheck-only (exact)
    } else {
        // --- pixels: normalize -> zn fp32 row-major [p][c] ---
        const int p = (blockIdx.x - NE / 4) * 256 + threadIdx.x;
        const int b = p >> 12, hw = p & (HW - 1);
        const float* zp = z + b * (EDIM * HW) + hw;
        float ss = 0.0f;
        for (int c = 0; c < EDIM; ++c) { const float v = zp[c * HW]; ss = fmaf(v, v, ss); }
        const float inv = 1.0f / fmaxf(sqrtf(ss), 1e-12f);
        for (int c4 = 0; c4 < 16; ++c4) {
            float4 o;
            o.x = zp[(c4 * 4 + 0) * HW] * inv;
            o.y = zp[(c4 * 4 + 1) * HW] * inv;
            o.z = zp[(c4 * 4 + 2) * HW] * inv;
            o.w = zp[(c4 * 4 + 3) * HW] * inv;
            *(float4*)(zn + p * EDIM + c4 * 4) = o;
        }
    }
}

// ---------------- k_mfma: split-K partial top-2 per pixel (dot max-space) ----
// Block: 4 waves x 32 pixels = 128 pixels, one codebook eighth (blockIdx.y).
// v = acc[r] = dot (zero-seeded; se const -> argmin dist == argmax dot);
// strict > keeps the earliest code on ties (codes ascend). Layouts (HW-verified):
// A[m=lane&15][k=quad*8+j], B[k=quad*8+j][n=lane&15], C/D row=(lane>>4)*4+reg,
// col=lane&15.
__global__ __launch_bounds__(256, 1) void k_mfma(const float* __restrict__ zn,
                                                 const short* __restrict__ esw,
                                                 float2* __restrict__ pv,   // [g][p] {b1,b2} (max-space)
                                                 unsigned* __restrict__ pi) // [g][p] i1
{
    __shared__ __align__(16) short es[2][NSTAGE * EDIM * 2];   // 2 x 8KB

    const int tid  = threadIdx.x;             // 0..255
    const int wave = tid >> 6, lane = tid & 63;
    const int quad = lane >> 4, col = lane & 15;
    const int p0   = blockIdx.x * 128 + wave * 32;  // wave's 32 pixels (2 sets)
    const int g    = blockIdx.y;                    // codebook eighth
    const int kbase = g * CPS;

    // A fragments: 2 sets of 16 pixels; fp32 zn -> bf16 hi + residual lo
    bf16x8 ah[2][2], al[2][2];
    #pragma unroll
    for (int s = 0; s < 2; ++s) {
        const float* zr = zn + (p0 + s * 16 + col) * EDIM;
        #pragma unroll
        for (int kc = 0; kc < 2; ++kc) {
            float f[8];
            *(float4*)(f + 0) = *(const float4*)(zr + kc * 32 + quad * 8 + 0);
            *(float4*)(f + 4) = *(const float4*)(zr + kc * 32 + quad * 8 + 4);
            #pragma unroll
            for (int i = 0; i < 8; ++i) {
                ah[s][kc][i] = f2bf_bits(f[i]);
                al[s][kc][i] = f2bf_bits(f[i] - bf_hi_f(f[i]));
            }
        }
    }

    // top-2 state in max-space (v = dot); b1 >= b2 invariant
    float b1[2][4], b2[2][4]; int i1[2][4];
    #pragma unroll
    for (int s = 0; s < 2; ++s)
        #pragma unroll
        for (int r = 0; r < 4; ++r) { b1[s][r] = -3.0e38f; b2[s][r] = -3.0e38f; i1[s][r] = 0; }

    // this wave's staging window: src and dst are both uniform + lane*16
    const int combo0 = wave * 2;              // 8 combos / 4 waves
    const char* gsrc0 = (const char*)esw + (size_t)kbase * 256
                        + combo0 * 1024 + lane * 16;
    // prologue: issue stage 0 -> buf 0
    #pragma unroll
    for (int it = 0; it < 2; ++it)
        gload_lds16(gsrc0 + it * 1024, (char*)&es[0][0] + (combo0 + it) * 1024);

    for (int nb = 0; nb < NSTG; ++nb) {
        const int cur = nb & 1;
        const int n0 = kbase + nb * NSTAGE;
        __syncthreads();   // vmcnt drained: buf[cur] complete; buf[cur^1] reusable
        if (nb + 1 < NSTG) {
            const char* gsrc = gsrc0 + (size_t)(nb + 1) * (NSTAGE * 256);
            #pragma unroll
            for (int it = 0; it < 2; ++it)
                gload_lds16(gsrc + it * 1024,
                            (char*)&es[cur ^ 1][0] + (combo0 + it) * 1024);
        }

        const short* esb = es[cur];
        #pragma unroll
        for (int sub = 0; sub < NSTAGE / 16; ++sub) {
            const short* base = esb + sub * 2048;
            const bf16x8 bh0 = *(const bf16x8*)(base + 0 * 512 + lane * 8);
            const bf16x8 bh1 = *(const bf16x8*)(base + 1 * 512 + lane * 8);
            const bf16x8 bl0 = *(const bf16x8*)(base + 2 * 512 + lane * 8);
            const bf16x8 bl1 = *(const bf16x8*)(base + 3 * 512 + lane * 8);
            const int nglob = n0 + sub * 16 + col;
            // two independent 6-deep chains, interleaved (dep distance 2)
            f32x4 a0 = {0.f, 0.f, 0.f, 0.f};
            f32x4 a1 = {0.f, 0.f, 0.f, 0.f};
            a0 = __builtin_amdgcn_mfma_f32_16x16x32_bf16(ah[0][0], bh0, a0, 0, 0, 0);
            a1 = __builtin_amdgcn_mfma_f32_16x16x32_bf16(ah[1][0], bh0, a1, 0, 0, 0);
            a0 = __builtin_amdgcn_mfma_f32_16x16x32_bf16(ah[0][0], bl0, a0, 0, 0, 0);
            a1 = __builtin_amdgcn_mfma_f32_16x16x32_bf16(ah[1][0], bl0, a1, 0, 0, 0);
            a0 = __builtin_amdgcn_mfma_f32_16x16x32_bf16(al[0][0], bh0, a0, 0, 0, 0);
            a1 = __builtin_amdgcn_mfma_f32_16x16x32_bf16(al[1][0], bh0, a1, 0, 0, 0);
            a0 = __builtin_amdgcn_mfma_f32_16x16x32_bf16(ah[0][1], bh1, a0, 0, 0, 0);
            a1 = __builtin_amdgcn_mfma_f32_16x16x32_bf16(ah[1][1], bh1, a1, 0, 0, 0);
            a0 = __builtin_amdgcn_mfma_f32_16x16x32_bf16(ah[0][1], bl1, a0, 0, 0, 0);
            a1 = __builtin_amdgcn_mfma_f32_16x16x32_bf16(ah[1][1], bl1, a1, 0, 0, 0);
            a0 = __builtin_amdgcn_mfma_f32_16x16x32_bf16(al[0][1], bh1, a0, 0, 0, 0);
            a1 = __builtin_amdgcn_mfma_f32_16x16x32_bf16(al[1][1], bh1, a1, 0, 0, 0);
            #pragma unroll
            for (int r = 0; r < 4; ++r) {
                const float v0 = a0[r];
                b2[0][r] = __builtin_amdgcn_fmed3f(v0, b2[0][r], b1[0][r]);
                const bool t0 = v0 > b1[0][r];               // strict >, n ascending
                b1[0][r] = fmaxf(b1[0][r], v0);
                i1[0][r] = t0 ? nglob : i1[0][r];
                const float v1 = a1[r];
                b2[1][r] = __builtin_amdgcn_fmed3f(v1, b2[1][r], b1[1][r]);
                const bool t1 = v1 > b1[1][r];
                b1[1][r] = fmaxf(b1[1][r], v1);
                i1[1][r] = t1 ? nglob : i1[1][r];
            }
        }
    }

    // merge top-2 across the 16 col-lanes (xor 1,2,4,8 stays inside quad group)
    #pragma unroll
    for (int m = 1; m <= 8; m <<= 1) {
        #pragma unroll
        for (int s = 0; s < 2; ++s)
            #pragma unroll
            for (int r = 0; r < 4; ++r) {
                const float ob1 = __shfl_xor(b1[s][r], m, 64);
                const int   oi1 = __shfl_xor(i1[s][r], m, 64);
                const float ob2 = __shfl_xor(b2[s][r], m, 64);
                const bool take = (ob1 > b1[s][r]) || (ob1 == b1[s][r] && oi1 < i1[s][r]);
                b2[s][r] = fmaxf(fmaxf(b2[s][r], ob2), fminf(b1[s][r], ob1));
                b1[s][r] = take ? ob1 : b1[s][r];
                i1[s][r] = take ? oi1 : i1[s][r];
            }
    }
    if (col == 0) {
        #pragma unroll
        for (int s = 0; s < 2; ++s)
            #pragma unroll
            for (int r = 0; r < 4; ++r) {
                const int p = p0 + s * 16 + quad * 4 + r;   // C/D row = quad*4 + r
                pv[g * NPIX + p] = make_float2(b1[s][r], b2[s][r]);
                pi[g * NPIX + p] = (unsigned)i1[s][r];
            }
    }
}

// ---------------- merge: combine KSPLIT partials (max-space), flag -----------
__global__ __launch_bounds__(256) void k_merge(const float2* __restrict__ pv,
                                               const unsigned* __restrict__ pi,
                                               unsigned* __restrict__ idx_arr,
                                               unsigned* __restrict__ list,
                                               unsigned* __restrict__ counter,
                                               unsigned long long* __restrict__ packed) {
    const int p = blockIdx.x * 256 + threadIdx.x;
    float2 v[KSPLIT]; unsigned ix[KSPLIT];
    #pragma unroll
    for (int gg = 0; gg < KSPLIT; ++gg) { v[gg] = pv[gg * NPIX + p]; ix[gg] = pi[gg * NPIX + p]; }
    // ascending group order + strict > == np first-occurrence tie semantics
    float b1 = v[0].x; unsigned i1 = ix[0]; int win = 0;
    #pragma unroll
    for (int gg = 1; gg < KSPLIT; ++gg)
        if (v[gg].x > b1) { b1 = v[gg].x; i1 = ix[gg]; win = gg; }
    float b2 = -3.0e38f;
    #pragma unroll
    for (int gg = 0; gg < KSPLIT; ++gg) {
        b2 = fmaxf(b2, v[gg].y);
        if (gg != win) b2 = fmaxf(b2, v[gg].x);
    }
    const bool fl = (b1 - b2 < MARGIN);   // dot-space gap
    idx_arr[p] = i1 | (fl ? 0x80000000u : 0u);
    if (fl) {
        packed[p] = ~0ull;
        const unsigned pos = atomicAdd(counter, 1u);
        if (pos < NPIX) list[pos] = p;
    }
}

// ---------------- recheck: exact fp32 argmin for flagged pixels --------------
// item = (flagged pixel, 512-code chunk). Coalesced: 4 codes x 16 lanes per
// b128 (contiguous 1KB from L2-resident e_norm); intra-16-lane shfl reduce.
__global__ __launch_bounds__(256) void k_recheck(const float* __restrict__ zn,
                                                 const float* __restrict__ e_norm,
                                                 const float* __restrict__ se_half,
                                                 const unsigned* __restrict__ list,
                                                 const unsigned* __restrict__ counter,
                                                 unsigned long long* __restrict__ packed) {
    const int lane  = threadIdx.x & 63;
    const int k     = lane >> 4;        // code-in-group 0..3
    const int m     = lane & 15;        // c4 index 0..15
    const int wglob = (blockIdx.x * 256 + threadIdx.x) >> 6;
    const int nwav  = (gridDim.x * 256) >> 6;
    int cnt = (int)*counter; if (cnt > NPIX) cnt = NPIX;
    const int nitems = cnt * 16;
    const float4* e4 = (const float4*)e_norm;

    for (int item = wglob; item < nitems; item += nwav) {
        const int p     = (int)list[item >> 4];
        const int chunk = item & 15;
        const float4 zv = *(const float4*)(zn + p * EDIM + m * 4);  // bcast/16 lanes
        float best = 3.0e38f; int bidx = 0;
        #pragma unroll 2
        for (int t = 0; t < 128; ++t) {                // 4 codes per iteration
            const int n = chunk * 512 + t * 4 + k;     // lane's code this iter
            const float4 ev = e4[n * 16 + m];          // lane-linear: 1KB contiguous
            float s = fmaf(zv.w, ev.w, fmaf(zv.z, ev.z,
                      fmaf(zv.y, ev.y, zv.x * ev.x)));
            s += __shfl_xor(s, 1, 64); s += __shfl_xor(s, 2, 64);
            s += __shfl_xor(s, 4, 64); s += __shfl_xor(s, 8, 64);
            const float d = se_half[n] - s;            // all 16 lanes same d
            if (d < best) { best = d; bidx = n; }      // lane's codes ascending
        }
        #pragma unroll
        for (int mm = 1; mm <= 32; mm <<= 1) {         // wave first-min
            const float ob = __shfl_xor(best, mm, 64);
            const int   oi = __shfl_xor(bidx, mm, 64);
            if (ob < best || (ob == best && oi < bidx)) { best = ob; bidx = oi; }
        }
        if (lane == 0) {
            const unsigned long long key =
                ((unsigned long long)order_u32(best) << 32) | (unsigned)bidx;
            atomicMin(&packed[p], key);
        }
    }
}

// ---------------- finalize: write indices + gather z_q (4 thr/pixel) ---------
__global__ __launch_bounds__(256) void k_finalize(const unsigned* __restrict__ idx_arr,
                                                  const unsigned long long* __restrict__ packed,
                                                  const float* __restrict__ e_norm,
                                                  float* __restrict__ out) {
    const int pl = threadIdx.x & 63;
    const int q  = threadIdx.x >> 6;                  // channel quarter 0..3
    const int p  = blockIdx.x * 64 + pl;
    const unsigned v = idx_arr[p];
    const int bidx = (v & 0x80000000u) ? (int)(packed[p] & 0xFFFFFFFFull)
                                       : (int)v;
    if (q == 0) out[NPIX * EDIM + p] = (float)bidx;
    const int b = p >> 12, hw = p & (HW - 1);
    float* op = out + b * (EDIM * HW) + hw;
    const float4* ep4 = (const float4*)(e_norm + bidx * EDIM + q * 16);
    #pragma unroll
    for (int j = 0; j < 4; ++j) {
        const float4 e = ep4[j];
        const int c = q * 16 + j * 4;
        op[(c + 0) * HW] = e.x; op[(c + 1) * HW] = e.y;   // coalesced per c
        op[(c + 2) * HW] = e.z; op[(c + 3) * HW] = e.w;
    }
}

extern "C" void kernel_launch(void* const* d_in, const int* in_sizes, int n_in,
                              void* d_out, int out_size, void* d_ws, size_t ws_size,
                              hipStream_t stream) {
    const float* z   = (const float*)d_in[0];
    const float* emb = (const float*)d_in[1];
    float* out = (float*)d_out;

    // workspace layout (~15.6 MB)
    float* e_norm  = (float*)d_ws;                       // 2 MB
    float* se_half = e_norm + NE * EDIM;                 // 32 KB
    short* esw = (short*)(se_half + NE);                 // 2 MB (swizzled hi+lo)
    float* zn = (float*)(esw + NE * EDIM * 2);           // 8 MB
    unsigned* idx_arr = (unsigned*)(zn + NPIX * EDIM);   // 128 KB
    unsigned* list    = idx_arr + NPIX;                  // 128 KB
    unsigned* counter = list + NPIX;                     // 4 B (+pad)
    unsigned long long* packed = (unsigned long long*)(counter + 64); // 256 KB
    float2*   pv = (float2*)(packed + NPIX);             // 2 MB
    unsigned* pi = (unsigned*)(pv + KSPLIT * NPIX);      // 1 MB

    k_prep<<<NE / 4 + NPIX / 256, 256, 0, stream>>>(emb, z, e_norm, se_half,
                                                    esw, zn, counter);
    k_mfma<<<dim3(NPIX / 128, KSPLIT), 256, 0, stream>>>(zn, esw, pv, pi);
    k_merge<<<NPIX / 256, 256, 0, stream>>>(pv, pi, idx_arr, list, counter, packed);
    k_recheck<<<1024, 256, 0, stream>>>(zn, e_norm, se_half, list, counter, packed);
    k_finalize<<<NPIX / 64, 256, 0, stream>>>(idx_arr, packed, e_norm, out);
}